// Round 12
// baseline (35.705 us; speedup 1.0000x reference)
//
#include <hip/hip_runtime.h>
#include <hip/hip_bf16.h>

#define BB 4
#define NN 256
#define KK 32
#define DD 32
#define HH 8
#define NE1 1025              // table rows per k: e = 0 (zeros) .. 1024
#define SL (NE1 * HH)         // ushorts per k-slice = 8200
#define NPTS (BB * NN * NN)   // 262144
#define NNSQ (NN * NN)        // 65536
#define TPB 256               // threads (= points) per block
#define NBLK (NPTS / TPB)     // 1024 blocks = 4 per CU

typedef __attribute__((ext_vector_type(8))) unsigned short ushort8;
typedef __attribute__((ext_vector_type(4))) int iv4;

__device__ __forceinline__ unsigned short f2bf(float f) {
    unsigned u = __float_as_uint(f);
    unsigned r = (u + 0x7FFFu + ((u >> 16) & 1u)) >> 16;
    return (unsigned short)r;
}

// ---------------------------------------------------------------------------
// Kernel A: proj[k][e][h] = sum_d feat[e][d] * W[k][d][h]  (bf16)
// Row e=0 stays zeros (feat[0] is the padding row) -> unconditional gather.
// t = k*1025 + e for t in [0, 32*1025).
// ---------------------------------------------------------------------------
__global__ __launch_bounds__(256) void build_proj_full(
    const float* __restrict__ feat,    // [1025][32]
    const float* __restrict__ w,       // [32][256] (d*8+h)
    unsigned short* __restrict__ proj) // [32][1025][8]
{
    int t = blockIdx.x * 256 + threadIdx.x;
    if (t >= KK * NE1) return;
    int k = t / NE1;
    int e = t - k * NE1;

    float acc[HH];
#pragma unroll
    for (int h = 0; h < HH; ++h) acc[h] = 0.0f;

    if (e > 0) {
        const float* frow = feat + (size_t)e * DD;
        const float* wrow = w + (size_t)k * DD * HH;
#pragma unroll
        for (int d = 0; d < DD; ++d) {
            float f = frow[d];
#pragma unroll
            for (int h = 0; h < HH; ++h) acc[h] = fmaf(f, wrow[d * HH + h], acc[h]);
        }
    }

    ushort8 o;
#pragma unroll
    for (int h = 0; h < HH; ++h) o[h] = f2bf(acc[h]);
    *(ushort8*)(proj + (size_t)t * HH) = o;
}

// ---------------------------------------------------------------------------
// Kernel B v12: barrier-free L2/L1 gather.
//  - idx transposed once into LDS via coalesced iv4 bursts (<=4 int4 live)
//  - 32 hops: 1 ds_read_u16 (conflict-free) + 1 unconditional global ushort8
//    gather from the L2-resident 513KB table (row 0 = zeros) + 8 bf16 adds
//  - no tbuf, no vmcnt choreography, one __syncthreads total; latency hidden
//    by 16 waves/CU x compiler-pipelined gathers
// E = ints per index element (2 = int64 input, 1 = int32).
// ---------------------------------------------------------------------------
template <int E>
__global__ __launch_bounds__(TPB, 4) void attn_bias_v12(
    const int* __restrict__ sp,               // [NPTS] (*E)
    const int* __restrict__ ei,               // [NPTS*KK] (*E)
    const float* __restrict__ semb,           // [512][8]
    const unsigned short* __restrict__ proj,  // [32][1025][8] bf16
    float* __restrict__ out)                  // [BB][HH][NNSQ]
{
    __shared__ unsigned short ibuf[KK][TPB + 2];   // 16.5KB

    const int tid = threadIdx.x;
    const int pg  = blockIdx.x * TPB + tid;

    const iv4* EI4 = (const iv4*)ei;
    const size_t bi4 = (size_t)blockIdx.x * TPB * (8 * E);  // iv4s per point = 8E

    // ---- transpose indices into ibuf (bursts of <=4 iv4 live) ----
    if (E == 2) {
#pragma unroll
        for (int b = 0; b < 4; ++b) {
            iv4 v0, v1, v2, v3;
            {
                int j = (4 * b + 0) * TPB + tid, pt = j >> 4, q = j & 15;
                v0 = EI4[bi4 + (size_t)pt * 16 + q];
            }
            {
                int j = (4 * b + 1) * TPB + tid, pt = j >> 4, q = j & 15;
                v1 = EI4[bi4 + (size_t)pt * 16 + q];
            }
            {
                int j = (4 * b + 2) * TPB + tid, pt = j >> 4, q = j & 15;
                v2 = EI4[bi4 + (size_t)pt * 16 + q];
            }
            {
                int j = (4 * b + 3) * TPB + tid, pt = j >> 4, q = j & 15;
                v3 = EI4[bi4 + (size_t)pt * 16 + q];
            }
            {
                int j = (4 * b + 0) * TPB + tid, pt = j >> 4, q = j & 15;
                ibuf[2 * q][pt] = (unsigned short)v0.x;
                ibuf[2 * q + 1][pt] = (unsigned short)v0.z;
            }
            {
                int j = (4 * b + 1) * TPB + tid, pt = j >> 4, q = j & 15;
                ibuf[2 * q][pt] = (unsigned short)v1.x;
                ibuf[2 * q + 1][pt] = (unsigned short)v1.z;
            }
            {
                int j = (4 * b + 2) * TPB + tid, pt = j >> 4, q = j & 15;
                ibuf[2 * q][pt] = (unsigned short)v2.x;
                ibuf[2 * q + 1][pt] = (unsigned short)v2.z;
            }
            {
                int j = (4 * b + 3) * TPB + tid, pt = j >> 4, q = j & 15;
                ibuf[2 * q][pt] = (unsigned short)v3.x;
                ibuf[2 * q + 1][pt] = (unsigned short)v3.z;
            }
        }
    } else {
#pragma unroll
        for (int b = 0; b < 2; ++b) {
            iv4 v0, v1, v2, v3;
            {
                int j = (4 * b + 0) * TPB + tid, pt = j >> 3, q = j & 7;
                v0 = EI4[bi4 + (size_t)pt * 8 + q];
            }
            {
                int j = (4 * b + 1) * TPB + tid, pt = j >> 3, q = j & 7;
                v1 = EI4[bi4 + (size_t)pt * 8 + q];
            }
            {
                int j = (4 * b + 2) * TPB + tid, pt = j >> 3, q = j & 7;
                v2 = EI4[bi4 + (size_t)pt * 8 + q];
            }
            {
                int j = (4 * b + 3) * TPB + tid, pt = j >> 3, q = j & 7;
                v3 = EI4[bi4 + (size_t)pt * 8 + q];
            }
            {
                int j = (4 * b + 0) * TPB + tid, pt = j >> 3, q = j & 7;
                ibuf[4 * q][pt] = (unsigned short)v0.x;
                ibuf[4 * q + 1][pt] = (unsigned short)v0.y;
                ibuf[4 * q + 2][pt] = (unsigned short)v0.z;
                ibuf[4 * q + 3][pt] = (unsigned short)v0.w;
            }
            {
                int j = (4 * b + 1) * TPB + tid, pt = j >> 3, q = j & 7;
                ibuf[4 * q][pt] = (unsigned short)v1.x;
                ibuf[4 * q + 1][pt] = (unsigned short)v1.y;
                ibuf[4 * q + 2][pt] = (unsigned short)v1.z;
                ibuf[4 * q + 3][pt] = (unsigned short)v1.w;
            }
            {
                int j = (4 * b + 2) * TPB + tid, pt = j >> 3, q = j & 7;
                ibuf[4 * q][pt] = (unsigned short)v2.x;
                ibuf[4 * q + 1][pt] = (unsigned short)v2.y;
                ibuf[4 * q + 2][pt] = (unsigned short)v2.z;
                ibuf[4 * q + 3][pt] = (unsigned short)v2.w;
            }
            {
                int j = (4 * b + 3) * TPB + tid, pt = j >> 3, q = j & 7;
                ibuf[4 * q][pt] = (unsigned short)v3.x;
                ibuf[4 * q + 1][pt] = (unsigned short)v3.y;
                ibuf[4 * q + 2][pt] = (unsigned short)v3.z;
                ibuf[4 * q + 3][pt] = (unsigned short)v3.w;
            }
        }
    }

    __syncthreads();   // the only barrier

    // ---- 32 unconditional gathers from the L2/L1-resident table ----
    float acc[HH];
#pragma unroll
    for (int h = 0; h < HH; ++h) acc[h] = 0.0f;
    int cnt = 0;

#pragma unroll
    for (int k = 0; k < KK; ++k) {
        int e = ibuf[k][tid];
        cnt += (e != 0);
        ushort8 w = *(const ushort8*)(proj + (size_t)k * SL + (size_t)e * HH);
#pragma unroll
        for (int h = 0; h < HH; ++h)
            acc[h] += __uint_as_float(((unsigned)w[h]) << 16);
    }

    // ---- epilogue: spatial bias + write ----
    int sv = (E == 2) ? (int)((const long long*)sp)[pg] : sp[pg];
    const float4* srow = (const float4*)(semb + (size_t)sv * HH);
    float4 s0v = srow[0], s1v = srow[1];
    float sb[HH] = {s0v.x, s0v.y, s0v.z, s0v.w, s1v.x, s1v.y, s1v.z, s1v.w};

    float inv = 1.0f / (float)(cnt ? cnt : 1);
    float* o = out + (size_t)(pg >> 16) * (HH * NNSQ) + (pg & (NNSQ - 1));
#pragma unroll
    for (int h = 0; h < HH; ++h)
        o[(size_t)h * NNSQ] = sb[h] + acc[h] * inv;
}

extern "C" void kernel_launch(void* const* d_in, const int* in_sizes, int n_in,
                              void* d_out, int out_size, void* d_ws, size_t ws_size,
                              hipStream_t stream) {
    const int*   sp = (const int*)d_in[0];    // spatial_pos  [4,256,256]
    const int*   ei = (const int*)d_in[1];    // edge_input   [4,256,256,32]
    const float* se = (const float*)d_in[2];  // spatial_emb  [512,8]
    const float* fe = (const float*)d_in[3];  // edge_feat_emb[1025,32]
    const float* pw = (const float*)d_in[4];  // edge_pos_emb [32,256]
    float* out = (float*)d_out;

    const bool i64 = (in_sizes[0] == 2 * NPTS);
    unsigned short* proj = (unsigned short*)d_ws;   // 32*1025*8*2 = 524,800 B

    build_proj_full<<<(KK * NE1 + 255) / 256, 256, 0, stream>>>(fe, pw, proj);

    if (i64) attn_bias_v12<2><<<NBLK, TPB, 0, stream>>>(sp, ei, se, proj, out);
    else     attn_bias_v12<1><<<NBLK, TPB, 0, stream>>>(sp, ei, se, proj, out);
}

// Round 14
// 27.280 us; speedup vs baseline: 1.3088x; 1.3088x over previous
//
#include <hip/hip_runtime.h>
#include <hip/hip_bf16.h>

#define BB 4
#define NN 256
#define KK 32
#define DD 32
#define HH 8
#define NROWS 1024            // proj rows: e = 1..1024 stored at e-1
#define NPTS (BB * NN * NN)   // 262144
#define NNSQ (NN * NN)        // 65536
#define TPB 1024              // threads (= points) per block
#define NBLK (NPTS / TPB)     // 256 blocks = 1 per CU
#define SLICE_US (NROWS * HH) // 8192 ushorts = 16KB per k-slice
#define SLOT_US  (2 * SLICE_US)
#define CMP_U32 (NPTS * 16)   // packed u16 hop-pairs: 16 per point
#define CMP_BYTES ((size_t)CMP_U32 * 4)                  // 16.78 MB
#define PROJ_BYTES ((size_t)KK * NROWS * HH * 2)         // 512 KB
#define NEED_WS (CMP_BYTES + PROJ_BYTES)

typedef __attribute__((ext_vector_type(8))) unsigned short ushort8;
typedef __attribute__((ext_vector_type(4))) int iv4;
typedef __attribute__((ext_vector_type(2))) int iv2;

#define FENCE  asm volatile("" ::: "memory")
#define LGKM0  asm volatile("s_waitcnt lgkmcnt(0)" ::: "memory")
#define BAR    __builtin_amdgcn_s_barrier()
#define VMW(n) asm volatile("s_waitcnt vmcnt(" #n ")" ::: "memory")

__device__ __forceinline__ unsigned short f2bf(float f) {
    unsigned u = __float_as_uint(f);
    unsigned r = (u + 0x7FFFu + ((u >> 16) & 1u)) >> 16;
    return (unsigned short)r;
}

__device__ __forceinline__ void gload16(const void* g, void* l) {
    __builtin_amdgcn_global_load_lds(
        (const __attribute__((address_space(1))) void*)g,
        (__attribute__((address_space(3))) void*)l,
        16, 0, 0);
}

__device__ __forceinline__ void build_one(int t, const float* __restrict__ feat,
                                          const float* __restrict__ w,
                                          unsigned short* __restrict__ proj) {
    // proj[k][e-1][h] = sum_d feat[e][d] * W[k][d][h], t = k*1024 + (e-1)
    int k = t >> 10;
    int e = (t & 1023) + 1;
    const float* frow = feat + (size_t)e * DD;
    const float* wrow = w + (size_t)k * DD * HH;
    float acc[HH];
#pragma unroll
    for (int h = 0; h < HH; ++h) acc[h] = 0.0f;
#pragma unroll
    for (int d = 0; d < DD; ++d) {
        float f = frow[d];
#pragma unroll
        for (int h = 0; h < HH; ++h) acc[h] = fmaf(f, wrow[d * HH + h], acc[h]);
    }
    ushort8 o;
#pragma unroll
    for (int h = 0; h < HH; ++h) o[h] = f2bf(acc[h]);
    *(ushort8*)(proj + (size_t)t * HH) = o;
}

// ---------------------------------------------------------------------------
// Standalone build (fallback path)
// ---------------------------------------------------------------------------
__global__ __launch_bounds__(256) void build_proj_bf16(
    const float* __restrict__ feat, const float* __restrict__ w,
    unsigned short* __restrict__ proj) {
    build_one(blockIdx.x * 256 + threadIdx.x, feat, w, proj);
}

// ---------------------------------------------------------------------------
// Fused pre-kernel: blocks 0..127 build proj; the rest stream-compact
// edge_input into packed u16 hop-pairs cmp[pt*16 + q] = e(2q) | e(2q+1)<<16.
// Pure coalesced stream, no barriers -> runs at HBM rate.
// ---------------------------------------------------------------------------
template <int E>
__global__ __launch_bounds__(256) void fused_pre(
    const int* __restrict__ ei, const float* __restrict__ feat,
    const float* __restrict__ w, unsigned* __restrict__ cmp,
    unsigned short* __restrict__ proj)
{
    int bid = blockIdx.x;
    int tid = threadIdx.x;
    if (bid < 128) { build_one(bid * 256 + tid, feat, w, proj); return; }

    const iv4* EI4 = (const iv4*)ei;
    size_t g = (size_t)(bid - 128) * 256 + tid;
    if (E == 2) {
        // iv4 g = int64 elems 2g,2g+1 (low words at .x,.z) -> pair index g
        iv4 v = EI4[g];
        cmp[g] = ((unsigned)v.x & 0xffffu) | ((unsigned)v.z << 16);
    } else {
        // iv4 g = int32 elems 4g..4g+3 -> pairs 2g,2g+1
        iv4 v = EI4[g];
        iv2 o;
        o.x = (int)(((unsigned)v.x & 0xffffu) | ((unsigned)v.y << 16));
        o.y = (int)(((unsigned)v.z & 0xffffu) | ((unsigned)v.w << 16));
        ((iv2*)cmp)[g] = o;
    }
}

// ---------------------------------------------------------------------------
// Main v14: idx-free pipeline. Each thread holds its OWN point's 16 packed
// pairs (64B, read from L3-hot cmp). 16 phases: STG2(p+2) into 3-slot
// gload_lds ring + 2 LDS gathers per phase; constant VMW(2) per phase.
// No ibuf, no transpose, no chunk choreography.
// ---------------------------------------------------------------------------
template <int E>
__global__ __launch_bounds__(TPB) void attn_bias_v14(
    const int* __restrict__ sp,               // [NPTS] (*E)
    const unsigned* __restrict__ cmp,         // [NPTS][16] packed pairs
    const float* __restrict__ semb,           // [512][8]
    const unsigned short* __restrict__ proj,  // [32][1024][8] bf16
    float* __restrict__ out)                  // [BB][HH][NNSQ]
{
    __shared__ __align__(16) unsigned short tbuf[3 * SLOT_US]; // 96KB ring
    __shared__ __align__(16) unsigned short zrow[8];

    const int tid = threadIdx.x;
    const int pg  = blockIdx.x * TPB + tid;

    float acc[HH];
#pragma unroll
    for (int h = 0; h < HH; ++h) acc[h] = 0.0f;
    int cnt = 0;

#define K2STG(q) do{                                                           \
        gload16(proj + (size_t)(2 * (q)) * SLICE_US + (size_t)tid * 8,         \
                &tbuf[((q) % 3) * SLOT_US + tid * 8]);                         \
        gload16(proj + (size_t)(2 * (q) + 1) * SLICE_US + (size_t)tid * 8,     \
                &tbuf[((q) % 3) * SLOT_US + SLICE_US + tid * 8]);              \
    }while(0)

#define K2HOP(p, pr) do{                                                       \
        unsigned _pr = (unsigned)(pr);                                         \
        int e0 = _pr & 0xffffu;                                                \
        int e1 = _pr >> 16;                                                    \
        cnt += (e0 != 0) + (e1 != 0);                                          \
        const unsigned short* tb = &tbuf[((p) % 3) * SLOT_US];                 \
        const unsigned short* a0 = e0 ? tb + (e0 - 1) * HH : zrow;             \
        const unsigned short* a1 = e1 ? tb + SLICE_US + (e1 - 1) * HH : zrow;  \
        ushort8 w0 = *(const ushort8*)a0;                                      \
        ushort8 w1 = *(const ushort8*)a1;                                      \
        _Pragma("unroll")                                                      \
        for (int h = 0; h < HH; ++h) {                                         \
            acc[h] += __uint_as_float(((unsigned)w0[h]) << 16);                \
            acc[h] += __uint_as_float(((unsigned)w1[h]) << 16);                \
        }                                                                      \
    }while(0)

#define K2PH(p, pr) do{                                                        \
        if ((p) <= 13) K2STG((p) + 2);                                         \
        K2HOP(p, pr);                                                          \
        FENCE; VMW(2); BAR;                                                    \
    }while(0)

    // ---------------- prologue ----------------
    int sv;
    if constexpr (E == 2) sv = (int)((const long long*)sp)[pg];
    else                  sv = sp[pg];
    FENCE;
    const iv4* C4 = (const iv4*)cmp;
    iv4 P0 = C4[(size_t)pg * 4 + 0];
    iv4 P1 = C4[(size_t)pg * 4 + 1];
    iv4 P2 = C4[(size_t)pg * 4 + 2];
    iv4 P3 = C4[(size_t)pg * 4 + 3];
    FENCE;
    K2STG(0); K2STG(1);
    if (tid == 0) *(float4*)zrow = make_float4(0.f, 0.f, 0.f, 0.f);
    FENCE;
    VMW(2);    // drains sv, P0-3, S0; keeps S1
    LGKM0;     // zrow visible
    BAR;

    // ---------------- 16 phases ----------------
    K2PH(0,  P0.x); K2PH(1,  P0.y); K2PH(2,  P0.z); K2PH(3,  P0.w);
    K2PH(4,  P1.x); K2PH(5,  P1.y); K2PH(6,  P1.z); K2PH(7,  P1.w);
    K2PH(8,  P2.x); K2PH(9,  P2.y); K2PH(10, P2.z); K2PH(11, P2.w);
    K2PH(12, P3.x);
    K2PH(13, P3.y);
    K2HOP(14, P3.z); FENCE; VMW(0); BAR;   // drains S15
    K2HOP(15, P3.w);

    // ---------------- epilogue ----------------
    const float4* srow = (const float4*)(semb + (size_t)sv * HH);
    float4 s0v = srow[0], s1v = srow[1];
    float sb[HH] = {s0v.x, s0v.y, s0v.z, s0v.w, s1v.x, s1v.y, s1v.z, s1v.w};

    float inv = 1.0f / (float)(cnt ? cnt : 1);
    float* o = out + (size_t)(pg >> 16) * (HH * NNSQ) + (pg & (NNSQ - 1));
#pragma unroll
    for (int h = 0; h < HH; ++h)
        o[(size_t)h * NNSQ] = sb[h] + acc[h] * inv;
}

// ---------------------------------------------------------------------------
// Fallback: verbatim v8 (passed, 25.8us) for small ws_size.
// ---------------------------------------------------------------------------
template <int E>
__global__ __launch_bounds__(TPB) void attn_bias_v8(
    const int* __restrict__ sp, const int* __restrict__ ei,
    const float* __restrict__ semb, const unsigned short* __restrict__ proj,
    float* __restrict__ out)
{
    __shared__ __align__(16) unsigned short tbuf[3 * SLOT_US];
    __shared__ __align__(16) unsigned short zrow[8];
    __shared__ unsigned int ibuf[2][4][NROWS + 4];

    const int tid = threadIdx.x;
    const int p0  = blockIdx.x * TPB;
    const int pg  = p0 + tid;

    constexpr int NC = (E == 2) ? 4 : 2;
    const iv4* EI4 = (const iv4*)ei;
    const size_t bi4 = (size_t)blockIdx.x * TPB * (8 * E);

    iv4 cv[NC];

    auto issueC = [&](int g) {
#pragma unroll
        for (int c = 0; c < NC; ++c) {
            if (E == 2) {
                int j = c * TPB + tid, pt = j >> 2, q = j & 3;
                cv[c] = EI4[bi4 + (size_t)pt * 16 + 4 * g + q];
            } else {
                int j = c * TPB + tid, pt = j >> 1, q = j & 1;
                cv[c] = EI4[bi4 + (size_t)pt * 8 + 2 * g + q];
            }
        }
    };
    auto writeC = [&](int nb) {
#pragma unroll
        for (int c = 0; c < NC; ++c) {
            if (E == 2) {
                int j = c * TPB + tid, pt = j >> 2, q = j & 3;
                ibuf[nb][q][pt] = ((unsigned)cv[c].x & 0xffffu) |
                                  ((unsigned)cv[c].z << 16);
            } else {
                int j = c * TPB + tid, pt = j >> 1, q = j & 1;
                ibuf[nb][2 * q][pt] = ((unsigned)cv[c].x & 0xffffu) |
                                      ((unsigned)cv[c].y << 16);
                ibuf[nb][2 * q + 1][pt] = ((unsigned)cv[c].z & 0xffffu) |
                                          ((unsigned)cv[c].w << 16);
            }
        }
    };
    auto stage2 = [&](int phn, int slot) {
        gload16(proj + (size_t)(2 * phn) * SLICE_US + tid * HH,
                &tbuf[slot * SLOT_US + tid * HH]);
        gload16(proj + (size_t)(2 * phn + 1) * SLICE_US + tid * HH,
                &tbuf[slot * SLOT_US + SLICE_US + tid * HH]);
    };

    float acc[HH];
#pragma unroll
    for (int h = 0; h < HH; ++h) acc[h] = 0.0f;
    int cnt = 0;

    auto dohops = [&](int slot, int gsel, int q) {
        unsigned pr = ibuf[gsel][q][tid];
        int e0 = pr & 0xffffu;
        int e1 = pr >> 16;
        cnt += (e0 != 0) + (e1 != 0);
        const unsigned short* tb = &tbuf[slot * SLOT_US];
        const unsigned short* a0 = e0 ? tb + (e0 - 1) * HH : zrow;
        const unsigned short* a1 = e1 ? tb + SLICE_US + (e1 - 1) * HH : zrow;
        ushort8 w0 = *(const ushort8*)a0;
        ushort8 w1 = *(const ushort8*)a1;
#pragma unroll
        for (int h = 0; h < HH; ++h) {
            acc[h] += __uint_as_float(((unsigned)w0[h]) << 16);
            acc[h] += __uint_as_float(((unsigned)w1[h]) << 16);
        }
    };

#define VMWA do { if constexpr (E == 2) VMW(6); else VMW(4); } while (0)
#define ENDPH do { FENCE; VMW(2); LGKM0; BAR; } while (0)

    int sv = (E == 2) ? (int)((const long long*)sp)[pg] : sp[pg];
    FENCE;
    issueC(0);
    FENCE;
    stage2(0, 0);
    stage2(1, 1);
    if (tid == 0) *(float4*)zrow = make_float4(0.f, 0.f, 0.f, 0.f);
    FENCE;
    writeC(0);
    issueC(1);
    FENCE;
    VMWA; LGKM0; BAR;

    stage2(2, 2);  FENCE; dohops(0, 0, 0); FENCE; VMWA; LGKM0; BAR;
    stage2(3, 0);  FENCE; dohops(1, 0, 1); ENDPH;
    stage2(4, 1);  FENCE; dohops(2, 0, 2); ENDPH;
    stage2(5, 2);  FENCE; dohops(0, 0, 3); writeC(1); issueC(2);
                   FENCE; VMWA; LGKM0; BAR;
    stage2(6, 0);  FENCE; dohops(1, 1, 0); FENCE; VMWA; LGKM0; BAR;
    stage2(7, 1);  FENCE; dohops(2, 1, 1); ENDPH;
    stage2(8, 2);  FENCE; dohops(0, 1, 2); ENDPH;
    stage2(9, 0);  FENCE; dohops(1, 1, 3); writeC(0); issueC(3);
                   FENCE; VMWA; LGKM0; BAR;
    stage2(10, 1); FENCE; dohops(2, 0, 0); FENCE; VMWA; LGKM0; BAR;
    stage2(11, 2); FENCE; dohops(0, 0, 1); ENDPH;
    stage2(12, 0); FENCE; dohops(1, 0, 2); ENDPH;
    stage2(13, 1); FENCE; dohops(2, 0, 3); writeC(1); ENDPH;
    stage2(14, 2); FENCE; dohops(0, 1, 0); ENDPH;
    stage2(15, 0); FENCE; dohops(1, 1, 1); ENDPH;
    dohops(2, 1, 2); FENCE; VMW(0); LGKM0; BAR;
    dohops(0, 1, 3);

    const float4* srow = (const float4*)(semb + (size_t)sv * HH);
    float4 s0v = srow[0], s1v = srow[1];
    float sb[HH] = {s0v.x, s0v.y, s0v.z, s0v.w, s1v.x, s1v.y, s1v.z, s1v.w};

    float inv = 1.0f / (float)(cnt ? cnt : 1);
    float* o = out + (size_t)(pg >> 16) * (HH * NNSQ) + (pg & (NNSQ - 1));
#pragma unroll
    for (int h = 0; h < HH; ++h)
        o[(size_t)h * NNSQ] = sb[h] + acc[h] * inv;
}

extern "C" void kernel_launch(void* const* d_in, const int* in_sizes, int n_in,
                              void* d_out, int out_size, void* d_ws, size_t ws_size,
                              hipStream_t stream) {
    const int*   sp = (const int*)d_in[0];
    const int*   ei = (const int*)d_in[1];
    const float* se = (const float*)d_in[2];
    const float* fe = (const float*)d_in[3];
    const float* pw = (const float*)d_in[4];
    float* out = (float*)d_out;

    const bool i64 = (in_sizes[0] == 2 * NPTS);

    if (ws_size >= NEED_WS) {
        unsigned* cmp = (unsigned*)d_ws;
        unsigned short* proj = (unsigned short*)((char*)d_ws + CMP_BYTES);
        if (i64) {
            fused_pre<2><<<128 + 16384, 256, 0, stream>>>(ei, fe, pw, cmp, proj);
            attn_bias_v14<2><<<NBLK, TPB, 0, stream>>>(sp, cmp, se, proj, out);
        } else {
            fused_pre<1><<<128 + 8192, 256, 0, stream>>>(ei, fe, pw, cmp, proj);
            attn_bias_v14<1><<<NBLK, TPB, 0, stream>>>(sp, cmp, se, proj, out);
        }
    } else {
        unsigned short* proj = (unsigned short*)d_ws;
        build_proj_bf16<<<128, 256, 0, stream>>>(fe, pw, proj);
        if (i64) attn_bias_v8<2><<<NBLK, TPB, 0, stream>>>(sp, ei, se, proj, out);
        else     attn_bias_v8<1><<<NBLK, TPB, 0, stream>>>(sp, ei, se, proj, out);
    }
}